// Round 9
// baseline (74.693 us; speedup 1.0000x reference)
//
#include <hip/hip_runtime.h>
#include <cstddef>

#define NB 8
#define TQ 2048
#define TV 2048
#define DD 128
#define KVT 32
#define NWV 4           // waves per block; chunk = 512 KV rows/wave (PROVEN shape)
#define CHW (TV / NWV)  // 512
#define NT  (CHW / KVT) // 16 tiles per wave

typedef _Float16 f16x8 __attribute__((ext_vector_type(8)));
typedef _Float16 f16x4 __attribute__((ext_vector_type(4)));
typedef float f32x4 __attribute__((ext_vector_type(4)));

// DPP row rotate (within 16-lane row)
template <int CTRL>
__device__ __forceinline__ float dpp_mov(float x) {
  return __builtin_bit_cast(float,
      __builtin_amdgcn_update_dpp(0, __builtin_bit_cast(int, x), CTRL, 0xF, 0xF, true));
}
__device__ __forceinline__ float rowmax16(float x) {
  x = fmaxf(x, dpp_mov<0x128>(x));  // row_ror:8
  x = fmaxf(x, dpp_mov<0x124>(x));  // row_ror:4
  x = fmaxf(x, dpp_mov<0x122>(x));  // row_ror:2
  x = fmaxf(x, dpp_mov<0x121>(x));  // row_ror:1
  return x;
}

// ------- prepass -----------------------------------------------------------
// qh  = scale * f16(q)                       [B][TQ][128]
// kh2 = f16(k) tiled: [B][64 kt][4 kc][32 row][32 dk]   (fragment = 1KB contiguous)
// vt2 = f16(v)^T tiled: [B][64 kt][128 d][32 kv]        (fragment = 1KB contiguous)
__global__ __launch_bounds__(256) void prepass_kernel(
    const float* __restrict__ q, const float* __restrict__ k,
    const float* __restrict__ v, const float* __restrict__ scale_p,
    _Float16* __restrict__ qh, _Float16* __restrict__ kh2, _Float16* __restrict__ vt2)
{
  __shared__ _Float16 tlds[32 * 34];
  const int tid = threadIdx.x;
  const int bid = blockIdx.x;
  if (bid < 2048) {                       // cast+scale Q
    const float sc = scale_p[0];
    size_t idx = (size_t)bid * 256 + tid;
    float4 x = ((const float4*)q)[idx];
    f16x4 h; h[0] = (_Float16)(sc * x.x); h[1] = (_Float16)(sc * x.y);
    h[2] = (_Float16)(sc * x.z); h[3] = (_Float16)(sc * x.w);
    ((f16x4*)qh)[idx] = h;
  } else if (bid < 2048 + 512) {          // K tiles: one 32x128 tile per block
    int tb = bid - 2048;                  // b*64 + kt
    int b = tb >> 6, kt = tb & 63;
    int row = tid >> 3, d0 = (tid & 7) * 4;
    const float* src = k + ((size_t)(b * TV + kt * 32 + row)) * DD;
    _Float16* dst = kh2 + ((size_t)(b * 64 + kt)) * 4096;
#pragma unroll
    for (int it = 0; it < 4; ++it) {      // kc = it
      float4 x = *(const float4*)(src + it * 32 + d0);
      f16x4 h; h[0] = (_Float16)x.x; h[1] = (_Float16)x.y;
      h[2] = (_Float16)x.z; h[3] = (_Float16)x.w;
      *(f16x4*)(dst + it * 1024 + row * 32 + d0) = h;
    }
  } else {                                // V transpose tiles 32x32
    int tb = bid - 2048 - 512;            // 8 b * 64 kt * 4 dt
    int b = tb >> 8, rem = tb & 255;
    int kt = rem >> 2, dt = rem & 3;
    int r = tid >> 3, c0 = (tid & 7) * 4;
    float4 x = *(const float4*)&v[((size_t)b * TV + kt * 32 + r) * DD + dt * 32 + c0];
    tlds[(c0 + 0) * 34 + r] = (_Float16)x.x;
    tlds[(c0 + 1) * 34 + r] = (_Float16)x.y;
    tlds[(c0 + 2) * 34 + r] = (_Float16)x.z;
    tlds[(c0 + 3) * 34 + r] = (_Float16)x.w;
    __syncthreads();
    int dl = tid >> 3, k0 = (tid & 7) * 4;
    f16x4 h;
#pragma unroll
    for (int i = 0; i < 4; ++i) h[i] = tlds[dl * 34 + k0 + i];
    size_t eidx = (((size_t)b * 64 + kt) * 128 + (dt * 32 + dl)) * 32 + k0;
    *(f16x4*)&vt2[eidx] = h;
  }
}

// ------- main: grid 512 (b=blk&7), 4 waves x 32 Q rows x 512-KV chunk ----------
// 2-tile interleaved pipeline: two independent {QK->sm->PV} chains per wave.
__global__ __launch_bounds__(256, 2) void attn_main(
    const _Float16* __restrict__ qh, const _Float16* __restrict__ kh2,
    const _Float16* __restrict__ vt2,
    const int* __restrict__ mask_q, const int* __restrict__ mask_v,
    float* __restrict__ out)
{
  __shared__ __align__(16) _Float16 plds_all[NWV][2][2][16 * 40]; // [wave][parity][rb]
  __shared__ __align__(16) float osh[32 * 132];
  __shared__ float msh[NWV][32], lsh[NWV][32];

  const int tid = threadIdx.x;
  const int w = tid >> 6;
  const int lane = tid & 63;
  const int l15 = lane & 15, lg = lane >> 4;

  const int b = blockIdx.x & 7;            // batch -> XCD affinity (proven mapping)
  const int qg = blockIdx.x >> 3;          // 0..63
  const int qbase = qg * 32;

  const _Float16* qhb = qh + ((size_t)b * TQ + qbase) * DD;
  const _Float16* ktiles = kh2 + (size_t)b * 64 * 4096;
  const _Float16* vtiles = vt2 + (size_t)b * 64 * 4096;
  const int* mvb = mask_v + b * TV;

  f16x8 qf[2][4];
#pragma unroll
  for (int rb = 0; rb < 2; ++rb)
#pragma unroll
    for (int kc = 0; kc < 4; ++kc)
      qf[rb][kc] = *(const f16x8*)(qhb + (size_t)(rb * 16 + l15) * DD + kc * 32 + lg * 8);

  f16x8 vones;
#pragma unroll
  for (int j = 0; j < 8; ++j) vones[j] = (_Float16)1.f;

  f32x4 acc[2][8];
  f32x4 accl[2];
#pragma unroll
  for (int rb = 0; rb < 2; ++rb) {
    accl[rb] = (f32x4){0.f, 0.f, 0.f, 0.f};
#pragma unroll
    for (int ct = 0; ct < 8; ++ct) acc[rb][ct] = (f32x4){0.f, 0.f, 0.f, 0.f};
  }
  float m[2][4];
#pragma unroll
  for (int rb = 0; rb < 2; ++rb)
#pragma unroll
    for (int r = 0; r < 4; ++r) m[rb][r] = -3.0e38f;

  const int tbase = w * NT;

  auto load_k = [&](int tile, f16x8 (&kf)[8]) {
    const _Float16* ktb = ktiles + (size_t)tile * 4096;
#pragma unroll
    for (int kc = 0; kc < 4; ++kc) {
      kf[2 * kc]     = *(const f16x8*)(ktb + kc * 1024 + l15 * 32 + lg * 8);
      kf[2 * kc + 1] = *(const f16x8*)(ktb + kc * 1024 + (16 + l15) * 32 + lg * 8);
    }
  };
  auto load_v = [&](int tile, f16x8 (&vf)[8]) {
    const _Float16* vtb = vtiles + (size_t)tile * 4096;
#pragma unroll
    for (int ct = 0; ct < 8; ++ct)
      vf[ct] = *(const f16x8*)(vtb + (ct * 16 + l15) * 32 + lg * 8);
  };
  auto do_qk = [&](f16x8 (&kf)[8], f32x4 (&s)[2][2]) {
    s[0][0] = (f32x4){0,0,0,0}; s[0][1] = (f32x4){0,0,0,0};
    s[1][0] = (f32x4){0,0,0,0}; s[1][1] = (f32x4){0,0,0,0};
    __builtin_amdgcn_s_setprio(1);
#pragma unroll
    for (int kc = 0; kc < 4; ++kc) {
      s[0][0] = __builtin_amdgcn_mfma_f32_16x16x32_f16(qf[0][kc], kf[2*kc],   s[0][0], 0, 0, 0);
      s[1][0] = __builtin_amdgcn_mfma_f32_16x16x32_f16(qf[1][kc], kf[2*kc],   s[1][0], 0, 0, 0);
      s[0][1] = __builtin_amdgcn_mfma_f32_16x16x32_f16(qf[0][kc], kf[2*kc+1], s[0][1], 0, 0, 0);
      s[1][1] = __builtin_amdgcn_mfma_f32_16x16x32_f16(qf[1][kc], kf[2*kc+1], s[1][1], 0, 0, 0);
    }
    __builtin_amdgcn_s_setprio(0);
  };
  // softmax: cheap per-lane grow check (exact for row test via __any);
  // DPP rowmax tree only on the rare rescale path.
  auto do_sm = [&](f32x4 (&s)[2][2], float a0, float a1, int par, f16x8 (&pa)[2]) {
#pragma unroll
    for (int rb = 0; rb < 2; ++rb) {
      _Float16* pl = plds_all[w][par][rb];
      float plm[4];
      bool grow = false;
#pragma unroll
      for (int r = 0; r < 4; ++r) {
        s[rb][0][r] += a0;
        s[rb][1][r] += a1;
        plm[r] = fmaxf(s[rb][0][r], s[rb][1][r]);
        grow = grow || (plm[r] > m[rb][r] + 8.f);
      }
      if (__any(grow)) {
        f32x4 alv;
#pragma unroll
        for (int r = 0; r < 4; ++r) {
          float pmx = rowmax16(plm[r]);
          float mn = fmaxf(m[rb][r], pmx);
          alv[r] = __expf(m[rb][r] - mn);
          m[rb][r] = mn;
        }
        accl[rb] *= alv;
#pragma unroll
        for (int ct = 0; ct < 8; ++ct) acc[rb][ct] *= alv;
      }
#pragma unroll
      for (int r = 0; r < 4; ++r) {
        float p0 = __expf(s[rb][0][r] - m[rb][r]);
        float p1 = __expf(s[rb][1][r] - m[rb][r]);
        int row = lg * 4 + r;
        pl[row * 40 + l15]      = (_Float16)p0;
        pl[row * 40 + 16 + l15] = (_Float16)p1;
      }
      pa[rb] = *(const f16x8*)(pl + l15 * 40 + lg * 8);
    }
  };
  auto do_pv = [&](f16x8 (&pa)[2], f16x8 (&vf)[8]) {
    __builtin_amdgcn_s_setprio(1);
#pragma unroll
    for (int ct = 0; ct < 8; ++ct) {
      acc[0][ct] = __builtin_amdgcn_mfma_f32_16x16x32_f16(pa[0], vf[ct], acc[0][ct], 0, 0, 0);
      acc[1][ct] = __builtin_amdgcn_mfma_f32_16x16x32_f16(pa[1], vf[ct], acc[1][ct], 0, 0, 0);
    }
    accl[0] = __builtin_amdgcn_mfma_f32_16x16x32_f16(pa[0], vones, accl[0], 0, 0, 0);
    accl[1] = __builtin_amdgcn_mfma_f32_16x16x32_f16(pa[1], vones, accl[1], 0, 0, 0);
    __builtin_amdgcn_s_setprio(0);
  };

#pragma unroll
  for (int tp = 0; tp < NT / 2; ++tp) {
    const int tileA = tbase + 2 * tp;
    const int tileB = tileA + 1;
    // ---- issue order: masks first, then kA, vA, kB, vB (monotone vmcnt waits)
    const int mA0i = mvb[tileA * KVT + l15];
    const int mA1i = mvb[tileA * KVT + 16 + l15];
    const int mB0i = mvb[tileB * KVT + l15];
    const int mB1i = mvb[tileB * KVT + 16 + l15];
    f16x8 kA[8], vA[8], kB[8], vB[8];
    load_k(tileA, kA);
    load_v(tileA, vA);
    load_k(tileB, kB);
    load_v(tileB, vB);
    const float aA0 = mA0i ? 0.f : -1e9f;
    const float aA1 = mA1i ? 0.f : -1e9f;
    const float aB0 = mB0i ? 0.f : -1e9f;
    const float aB1 = mB1i ? 0.f : -1e9f;

    f32x4 sA[2][2], sB[2][2];
    f16x8 paA[2], paB[2];
    do_qk(kA, sA);            // waits only kA
    do_qk(kB, sB);            // independent chain B starts early
    do_sm(sA, aA0, aA1, 0, paA);
    do_pv(paA, vA);
    do_sm(sB, aB0, aB1, 1, paB);
    do_pv(paB, vB);
  }

  // ---- publish per-wave stats ----
  if (l15 == 0) {
#pragma unroll
    for (int rb = 0; rb < 2; ++rb)
#pragma unroll
      for (int r = 0; r < 4; ++r) {
        msh[w][rb * 16 + lg * 4 + r] = m[rb][r];
        lsh[w][rb * 16 + lg * 4 + r] = accl[rb][r];
      }
  }
  __syncthreads();

  float coef[2][4];
#pragma unroll
  for (int rb = 0; rb < 2; ++rb)
#pragma unroll
    for (int r = 0; r < 4; ++r) {
      int row = rb * 16 + lg * 4 + r;
      float mstar = msh[0][row];
#pragma unroll
      for (int wv = 1; wv < NWV; ++wv) mstar = fmaxf(mstar, msh[wv][row]);
      coef[rb][r] = __expf(m[rb][r] - mstar);
    }

#pragma unroll
  for (int wv = 0; wv < NWV; ++wv) {
    if (w == wv) {
#pragma unroll
      for (int rb = 0; rb < 2; ++rb)
#pragma unroll
        for (int ct = 0; ct < 8; ++ct)
#pragma unroll
          for (int r = 0; r < 4; ++r) {
            int idx = (rb * 16 + lg * 4 + r) * 132 + ct * 16 + l15;
            float val = coef[rb][r] * acc[rb][ct][r];
            if (wv == 0) osh[idx] = val; else osh[idx] += val;
          }
    }
    __syncthreads();
  }

  // ---- final normalize + query-mask + store ----
  {
    const int row = tid >> 3;            // 0..31
    const int cg = (tid & 7) * 16;       // 0..112
    float mstar = msh[0][row];
#pragma unroll
    for (int wv = 1; wv < NWV; ++wv) mstar = fmaxf(mstar, msh[wv][row]);
    float lstar = 0.f;
#pragma unroll
    for (int wv = 0; wv < NWV; ++wv)
      lstar += __expf(msh[wv][row] - mstar) * lsh[wv][row];
    const int qr = qbase + row;
    const float f = ((mask_q[(size_t)b * TQ + qr] != 0) ? 1.f : 0.f) / lstar;
    float* orow = out + ((size_t)b * TQ + qr) * DD + cg;
#pragma unroll
    for (int i4 = 0; i4 < 4; ++i4) {
      float4 p = *(float4*)&osh[row * 132 + cg + i4 * 4];
      float4 o; o.x = p.x * f; o.y = p.y * f; o.z = p.z * f; o.w = p.w * f;
      *(float4*)(orow + i4 * 4) = o;
    }
  }
}

// ---------------- fallback (round-1 kernel) if ws too small --------------------
__global__ __launch_bounds__(64, 4) void attn_f32_kernel(
    const float* __restrict__ q, const float* __restrict__ v,
    const float* __restrict__ k, const float* __restrict__ scale_p,
    const int* __restrict__ mask_q, const int* __restrict__ mask_v,
    float* __restrict__ out)
{
  __shared__ __align__(16) _Float16 plds[16 * 40];
  const int lane = threadIdx.x & 63;
  const int l15 = lane & 15, lg = lane >> 4;
  const int qblocks = TQ / 16;
  const int b = blockIdx.x / qblocks, qb = blockIdx.x % qblocks;
  const int qbase = qb * 16;
  const float scale = scale_p[0];
  const float* qp = q + ((size_t)b * TQ + qbase) * DD;
  const float* kbase = k + (size_t)b * TV * DD;
  const float* vbase = v + (size_t)b * TV * DD;
  const int* mvb = mask_v + b * TV;
  f16x8 qf[4];
#pragma unroll
  for (int kc = 0; kc < 4; ++kc) {
    float4 a = *(const float4*)(qp + (size_t)l15 * DD + kc * 32 + lg * 8);
    float4 bb = *(const float4*)(qp + (size_t)l15 * DD + kc * 32 + lg * 8 + 4);
    f16x8 h; h[0]=(_Float16)a.x;h[1]=(_Float16)a.y;h[2]=(_Float16)a.z;h[3]=(_Float16)a.w;
    h[4]=(_Float16)bb.x;h[5]=(_Float16)bb.y;h[6]=(_Float16)bb.z;h[7]=(_Float16)bb.w;
    qf[kc]=h;
  }
  f32x4 acc[8];
#pragma unroll
  for (int i = 0; i < 8; ++i) acc[i] = (f32x4){0.f,0.f,0.f,0.f};
  float m[4], lsum[4];
#pragma unroll
  for (int r = 0; r < 4; ++r) { m[r] = -3.0e38f; lsum[r] = 0.f; }
  for (int kt = 0; kt < TV; kt += KVT) {
    f32x4 s0 = {0,0,0,0}, s1 = {0,0,0,0};
#pragma unroll
    for (int kc = 0; kc < 4; ++kc) {
      const float* kp0 = kbase + (size_t)(kt + l15) * DD + kc * 32 + lg * 8;
      float4 a = *(const float4*)kp0; float4 bb = *(const float4*)(kp0 + 4);
      f16x8 kf0; kf0[0]=(_Float16)a.x;kf0[1]=(_Float16)a.y;kf0[2]=(_Float16)a.z;kf0[3]=(_Float16)a.w;
      kf0[4]=(_Float16)bb.x;kf0[5]=(_Float16)bb.y;kf0[6]=(_Float16)bb.z;kf0[7]=(_Float16)bb.w;
      s0 = __builtin_amdgcn_mfma_f32_16x16x32_f16(qf[kc], kf0, s0, 0, 0, 0);
      const float* kp1 = kbase + (size_t)(kt + 16 + l15) * DD + kc * 32 + lg * 8;
      a = *(const float4*)kp1; bb = *(const float4*)(kp1 + 4);
      f16x8 kf1; kf1[0]=(_Float16)a.x;kf1[1]=(_Float16)a.y;kf1[2]=(_Float16)a.z;kf1[3]=(_Float16)a.w;
      kf1[4]=(_Float16)bb.x;kf1[5]=(_Float16)bb.y;kf1[6]=(_Float16)bb.z;kf1[7]=(_Float16)bb.w;
      s1 = __builtin_amdgcn_mfma_f32_16x16x32_f16(qf[kc], kf1, s1, 0, 0, 0);
    }
    const float a0 = (mvb[kt + l15] != 0) ? 0.f : -1e9f;
    const float a1 = (mvb[kt + 16 + l15] != 0) ? 0.f : -1e9f;
    float pmx[4];
#pragma unroll
    for (int r = 0; r < 4; ++r) {
      s0[r] = s0[r] * scale + a0; s1[r] = s1[r] * scale + a1;
      pmx[r] = fmaxf(s0[r], s1[r]);
    }
#pragma unroll
    for (int off = 1; off < 16; off <<= 1)
#pragma unroll
      for (int r = 0; r < 4; ++r) pmx[r] = fmaxf(pmx[r], __shfl_xor(pmx[r], off, 64));
    float al[4], ps[4];
#pragma unroll
    for (int r = 0; r < 4; ++r) {
      float mn = fmaxf(m[r], pmx[r]);
      al[r] = __expf(m[r] - mn); m[r] = mn;
      float p0 = __expf(s0[r] - mn), p1 = __expf(s1[r] - mn);
      ps[r] = p0 + p1;
      int row = lg * 4 + r;
      plds[row * 40 + l15] = (_Float16)p0;
      plds[row * 40 + 16 + l15] = (_Float16)p1;
    }
#pragma unroll
    for (int off = 1; off < 16; off <<= 1)
#pragma unroll
      for (int r = 0; r < 4; ++r) ps[r] += __shfl_xor(ps[r], off, 64);
#pragma unroll
    for (int r = 0; r < 4; ++r) {
      lsum[r] = lsum[r] * al[r] + ps[r];
#pragma unroll
      for (int ct = 0; ct < 8; ++ct) acc[ct][r] *= al[r];
    }
    f16x8 pa = *(const f16x8*)&plds[l15 * 40 + lg * 8];
#pragma unroll
    for (int ct = 0; ct < 8; ++ct) {
      const float* vp = vbase + (size_t)(kt + lg * 8) * DD + ct * 16 + l15;
      f16x8 vfx;
#pragma unroll
      for (int j = 0; j < 8; ++j) vfx[j] = (_Float16)vp[(size_t)j * DD];
      acc[ct] = __builtin_amdgcn_mfma_f32_16x16x32_f16(pa, vfx, acc[ct], 0, 0, 0);
    }
  }
  const int* mqb = mask_q + b * TQ;
#pragma unroll
  for (int r = 0; r < 4; ++r) {
    int row = lg * 4 + r;
    int qr = qbase + row;
    float f = ((mqb[qr] != 0) ? 1.f : 0.f) / lsum[r];
    float* orow = out + ((size_t)b * TQ + qr) * DD;
#pragma unroll
    for (int ct = 0; ct < 8; ++ct) orow[ct * 16 + l15] = acc[ct][r] * f;
  }
}

extern "C" void kernel_launch(void* const* d_in, const int* in_sizes, int n_in,
                              void* d_out, int out_size, void* d_ws, size_t ws_size,
                              hipStream_t stream) {
  const float* q      = (const float*)d_in[0];
  const float* v      = (const float*)d_in[1];
  const float* k      = (const float*)d_in[2];
  const float* scale  = (const float*)d_in[3];
  const int*   mask_q = (const int*)d_in[4];
  const int*   mask_v = (const int*)d_in[5];
  float* out = (float*)d_out;

  const size_t need = 3ull * NB * TV * DD * sizeof(_Float16);  // 12 MB
  if (ws_size >= need) {
    _Float16* qh  = (_Float16*)d_ws;
    _Float16* kh2 = qh + (size_t)NB * TQ * DD;
    _Float16* vt2 = kh2 + (size_t)NB * TV * DD;
    hipLaunchKernelGGL(prepass_kernel, dim3(2048 + 512 + 2048), dim3(256), 0, stream,
                       q, k, v, scale, qh, kh2, vt2);
    hipLaunchKernelGGL(attn_main, dim3(NB * (TQ / 32)), dim3(256), 0, stream,
                       qh, kh2, vt2, mask_q, mask_v, out);
  } else {
    hipLaunchKernelGGL(attn_f32_kernel, dim3(NB * (TQ / 16)), dim3(64), 0, stream,
                       q, v, k, scale, mask_q, mask_v, out);
  }
}

// Round 11
// 56.377 us; speedup vs baseline: 1.3249x; 1.3249x over previous
//
#include <hip/hip_runtime.h>
#include <cstddef>

#define NB 8
#define TQ 2048
#define TV 2048
#define DD 128
#define KVT 32
#define NWV 4           // waves per block; chunk = 512 KV rows/wave (PROVEN shape)
#define CHW (TV / NWV)  // 512
#define NT  (CHW / KVT) // 16 tiles per wave
#define LOG2E 1.4426950408889634f

typedef _Float16 f16x8 __attribute__((ext_vector_type(8)));
typedef _Float16 f16x4 __attribute__((ext_vector_type(4)));
typedef float f32x4 __attribute__((ext_vector_type(4)));

__device__ __forceinline__ float fast_exp2(float x) {
  return __builtin_amdgcn_exp2f(x);      // v_exp_f32 (computes 2^x)
}

// DPP row rotate (within 16-lane row)
template <int CTRL>
__device__ __forceinline__ float dpp_mov(float x) {
  return __builtin_bit_cast(float,
      __builtin_amdgcn_update_dpp(0, __builtin_bit_cast(int, x), CTRL, 0xF, 0xF, true));
}
__device__ __forceinline__ float rowmax16(float x) {
  x = fmaxf(x, dpp_mov<0x128>(x));  // row_ror:8
  x = fmaxf(x, dpp_mov<0x124>(x));  // row_ror:4
  x = fmaxf(x, dpp_mov<0x122>(x));  // row_ror:2
  x = fmaxf(x, dpp_mov<0x121>(x));  // row_ror:1
  return x;
}

// ------- prepass (K/V only; Q-cast fused into main) -------------------------
// kh2 = f16(k) tiled: [B][64 kt][4 kc][32 row][32 dk]   (fragment = 1KB contiguous)
// vt2 = f16(v)^T tiled: [B][64 kt][128 d][32 kv]        (fragment = 1KB contiguous)
__global__ __launch_bounds__(256) void prepass_kernel(
    const float* __restrict__ k, const float* __restrict__ v,
    _Float16* __restrict__ kh2, _Float16* __restrict__ vt2)
{
  __shared__ _Float16 tlds[32 * 34];
  const int tid = threadIdx.x;
  const int bid = blockIdx.x;
  if (bid < 512) {                        // K tiles: one 32x128 tile per block
    int b = bid >> 6, kt = bid & 63;
    int row = tid >> 3, d0 = (tid & 7) * 4;
    const float* src = k + ((size_t)(b * TV + kt * 32 + row)) * DD;
    _Float16* dst = kh2 + ((size_t)(b * 64 + kt)) * 4096;
#pragma unroll
    for (int it = 0; it < 4; ++it) {      // kc = it
      float4 x = *(const float4*)(src + it * 32 + d0);
      f16x4 h; h[0] = (_Float16)x.x; h[1] = (_Float16)x.y;
      h[2] = (_Float16)x.z; h[3] = (_Float16)x.w;
      *(f16x4*)(dst + it * 1024 + row * 32 + d0) = h;
    }
  } else {                                // V transpose tiles 32x32
    int tb = bid - 512;                   // 8 b * 64 kt * 4 dt
    int b = tb >> 8, rem = tb & 255;
    int kt = rem >> 2, dt = rem & 3;
    int r = tid >> 3, c0 = (tid & 7) * 4;
    float4 x = *(const float4*)&v[((size_t)b * TV + kt * 32 + r) * DD + dt * 32 + c0];
    tlds[(c0 + 0) * 34 + r] = (_Float16)x.x;
    tlds[(c0 + 1) * 34 + r] = (_Float16)x.y;
    tlds[(c0 + 2) * 34 + r] = (_Float16)x.z;
    tlds[(c0 + 3) * 34 + r] = (_Float16)x.w;
    __syncthreads();
    int dl = tid >> 3, k0 = (tid & 7) * 4;
    f16x4 h;
#pragma unroll
    for (int i = 0; i < 4; ++i) h[i] = tlds[dl * 34 + k0 + i];
    size_t eidx = (((size_t)b * 64 + kt) * 128 + (dt * 32 + dl)) * 32 + k0;
    *(f16x4*)&vt2[eidx] = h;
  }
}

// ------- main: grid 512 (b=blk&7), 4 waves x 32 Q rows x 512-KV chunk ----------
// Zero in-loop scalar loads (mask preloaded); post-use K/V prefetch; exp2 domain.
__global__ __launch_bounds__(256, 2) void attn_main(
    const float* __restrict__ q, const float* __restrict__ scale_p,
    const _Float16* __restrict__ kh2, const _Float16* __restrict__ vt2,
    const int* __restrict__ mask_q, const int* __restrict__ mask_v,
    float* __restrict__ out)
{
  __shared__ __align__(16) _Float16 plds_all[NWV][2][16 * 40];
  __shared__ __align__(16) float osh[32 * 132];
  __shared__ float msh[NWV][32], lsh[NWV][32];

  const int tid = threadIdx.x;
  const int w = tid >> 6;
  const int lane = tid & 63;
  const int l15 = lane & 15, lg = lane >> 4;

  const int b = blockIdx.x & 7;            // batch -> XCD affinity (proven mapping)
  const int qg = blockIdx.x >> 3;          // 0..63
  const int qbase = qg * 32;
  const int kv0 = w * CHW;

  const _Float16* ktiles = kh2 + (size_t)b * 64 * 4096;
  const _Float16* vtiles = vt2 + (size_t)b * 64 * 4096;
  const int* mvb = mask_v + b * TV;

  // ---- fused Q cast with scale*log2e ----
  const float sc2 = scale_p[0] * LOG2E;
  f16x8 qf[2][4];
#pragma unroll
  for (int rb = 0; rb < 2; ++rb)
#pragma unroll
    for (int kc = 0; kc < 4; ++kc) {
      const float* qp = q + ((size_t)b * TQ + qbase + rb * 16 + l15) * DD + kc * 32 + lg * 8;
      float4 xa = *(const float4*)qp;
      float4 xb = *(const float4*)(qp + 4);
      f16x8 h;
      h[0] = (_Float16)(sc2 * xa.x); h[1] = (_Float16)(sc2 * xa.y);
      h[2] = (_Float16)(sc2 * xa.z); h[3] = (_Float16)(sc2 * xa.w);
      h[4] = (_Float16)(sc2 * xb.x); h[5] = (_Float16)(sc2 * xb.y);
      h[6] = (_Float16)(sc2 * xb.z); h[7] = (_Float16)(sc2 * xb.w);
      qf[rb][kc] = h;
    }

  // ---- mask preload: 16 packed f16-bias regs (0 or -60000) ----
  const unsigned short HBIAS = __builtin_bit_cast(unsigned short, (_Float16)(-60000.0f));
  unsigned mbp[NT];
#pragma unroll
  for (int t = 0; t < NT; ++t) {
    unsigned h0 = (mvb[kv0 + t * KVT + l15]      != 0) ? 0u : (unsigned)HBIAS;
    unsigned h1 = (mvb[kv0 + t * KVT + 16 + l15] != 0) ? 0u : (unsigned)HBIAS;
    mbp[t] = h0 | (h1 << 16);
  }

  f16x8 vones;
#pragma unroll
  for (int j = 0; j < 8; ++j) vones[j] = (_Float16)1.f;

  f32x4 acc[2][8];
  f32x4 accl[2];
#pragma unroll
  for (int rb = 0; rb < 2; ++rb) {
    accl[rb] = (f32x4){0.f, 0.f, 0.f, 0.f};
#pragma unroll
    for (int ct = 0; ct < 8; ++ct) acc[rb][ct] = (f32x4){0.f, 0.f, 0.f, 0.f};
  }
  float m[2][4];
#pragma unroll
  for (int rb = 0; rb < 2; ++rb)
#pragma unroll
    for (int r = 0; r < 4; ++r) m[rb][r] = -3.0e38f;

  const int tbase = w * NT;

  f16x8 kbuf[8], vbuf[8];
  // prologue: K(0) then V(0)
  {
    const _Float16* ktb = ktiles + (size_t)tbase * 4096;
#pragma unroll
    for (int kc = 0; kc < 4; ++kc) {
      kbuf[2 * kc]     = *(const f16x8*)(ktb + kc * 1024 + l15 * 32 + lg * 8);
      kbuf[2 * kc + 1] = *(const f16x8*)(ktb + kc * 1024 + (16 + l15) * 32 + lg * 8);
    }
    const _Float16* vtb = vtiles + (size_t)tbase * 4096;
#pragma unroll
    for (int ct = 0; ct < 8; ++ct)
      vbuf[ct] = *(const f16x8*)(vtb + (ct * 16 + l15) * 32 + lg * 8);
  }

#pragma unroll
  for (int t = 0; t < NT; ++t) {
    const int tile = tbase + t;

    // ---- QK^T on kbuf (waits only K(t)) ----
    f32x4 s[2][2];
    s[0][0] = (f32x4){0,0,0,0}; s[0][1] = (f32x4){0,0,0,0};
    s[1][0] = (f32x4){0,0,0,0}; s[1][1] = (f32x4){0,0,0,0};
    __builtin_amdgcn_s_setprio(1);
#pragma unroll
    for (int kc = 0; kc < 4; ++kc) {
      s[0][0] = __builtin_amdgcn_mfma_f32_16x16x32_f16(qf[0][kc], kbuf[2*kc],   s[0][0], 0, 0, 0);
      s[1][0] = __builtin_amdgcn_mfma_f32_16x16x32_f16(qf[1][kc], kbuf[2*kc],   s[1][0], 0, 0, 0);
      s[0][1] = __builtin_amdgcn_mfma_f32_16x16x32_f16(qf[0][kc], kbuf[2*kc+1], s[0][1], 0, 0, 0);
      s[1][1] = __builtin_amdgcn_mfma_f32_16x16x32_f16(qf[1][kc], kbuf[2*kc+1], s[1][1], 0, 0, 0);
    }
    __builtin_amdgcn_s_setprio(0);

    // ---- post-use K prefetch into kbuf (WAR-safe: issued after QK MFMAs) ----
    if (t + 1 < NT) {
      const _Float16* ktb = ktiles + (size_t)(tile + 1) * 4096;
#pragma unroll
      for (int kc = 0; kc < 4; ++kc) {
        kbuf[2 * kc]     = *(const f16x8*)(ktb + kc * 1024 + l15 * 32 + lg * 8);
        kbuf[2 * kc + 1] = *(const f16x8*)(ktb + kc * 1024 + (16 + l15) * 32 + lg * 8);
      }
    }

    // ---- softmax in exp2 domain; no loads (bias from regs) ----
    const float b0 = (float)__builtin_bit_cast(_Float16, (unsigned short)(mbp[t] & 0xFFFFu));
    const float b1 = (float)__builtin_bit_cast(_Float16, (unsigned short)(mbp[t] >> 16));
    f16x8 pa[2];
#pragma unroll
    for (int rb = 0; rb < 2; ++rb) {
      float plm[4];
      bool grow = false;
#pragma unroll
      for (int r = 0; r < 4; ++r) {
        s[rb][0][r] += b0;
        s[rb][1][r] += b1;
        plm[r] = fmaxf(s[rb][0][r], s[rb][1][r]);
        grow = grow || (plm[r] > m[rb][r] + 11.5f);
      }
      if (__any(grow)) {                 // rare rescale path
        f32x4 alv;
#pragma unroll
        for (int r = 0; r < 4; ++r) {
          float pmx = rowmax16(plm[r]);
          float mn = fmaxf(m[rb][r], pmx);
          alv[r] = fast_exp2(m[rb][r] - mn);
          m[rb][r] = mn;
        }
        accl[rb] *= alv;
#pragma unroll
        for (int ct = 0; ct < 8; ++ct) acc[rb][ct] *= alv;
      }
      _Float16* pl = plds_all[w][rb];
#pragma unroll
      for (int r = 0; r < 4; ++r) {
        float p0 = fast_exp2(s[rb][0][r] - m[rb][r]);
        float p1 = fast_exp2(s[rb][1][r] - m[rb][r]);
        int row = lg * 4 + r;
        pl[row * 40 + l15]      = (_Float16)p0;
        pl[row * 40 + 16 + l15] = (_Float16)p1;
      }
      pa[rb] = *(const f16x8*)(pl + l15 * 40 + lg * 8);
    }

    // ---- PV (waits only V(t)) + ones-column row-sum ----
    __builtin_amdgcn_s_setprio(1);
#pragma unroll
    for (int ct = 0; ct < 8; ++ct) {
      acc[0][ct] = __builtin_amdgcn_mfma_f32_16x16x32_f16(pa[0], vbuf[ct], acc[0][ct], 0, 0, 0);
      acc[1][ct] = __builtin_amdgcn_mfma_f32_16x16x32_f16(pa[1], vbuf[ct], acc[1][ct], 0, 0, 0);
    }
    accl[0] = __builtin_amdgcn_mfma_f32_16x16x32_f16(pa[0], vones, accl[0], 0, 0, 0);
    accl[1] = __builtin_amdgcn_mfma_f32_16x16x32_f16(pa[1], vones, accl[1], 0, 0, 0);
    __builtin_amdgcn_s_setprio(0);

    // ---- post-use V prefetch into vbuf (WAR-safe: issued after PV MFMAs) ----
    if (t + 1 < NT) {
      const _Float16* vtb = vtiles + (size_t)(tile + 1) * 4096;
#pragma unroll
      for (int ct = 0; ct < 8; ++ct)
        vbuf[ct] = *(const f16x8*)(vtb + (ct * 16 + l15) * 32 + lg * 8);
    }
  }

  // ---- publish per-wave stats ----
  if (l15 == 0) {
#pragma unroll
    for (int rb = 0; rb < 2; ++rb)
#pragma unroll
      for (int r = 0; r < 4; ++r) {
        msh[w][rb * 16 + lg * 4 + r] = m[rb][r];
        lsh[w][rb * 16 + lg * 4 + r] = accl[rb][r];
      }
  }
  __syncthreads();

  float coef[2][4];
#pragma unroll
  for (int rb = 0; rb < 2; ++rb)
#pragma unroll
    for (int r = 0; r < 4; ++r) {
      int row = rb * 16 + lg * 4 + r;
      float mstar = msh[0][row];
#pragma unroll
      for (int wv = 1; wv < NWV; ++wv) mstar = fmaxf(mstar, msh[wv][row]);
      coef[rb][r] = fast_exp2(m[rb][r] - mstar);
    }

#pragma unroll
  for (int wv = 0; wv < NWV; ++wv) {
    if (w == wv) {
#pragma unroll
      for (int rb = 0; rb < 2; ++rb)
#pragma unroll
        for (int ct = 0; ct < 8; ++ct)
#pragma unroll
          for (int r = 0; r < 4; ++r) {
            int idx = (rb * 16 + lg * 4 + r) * 132 + ct * 16 + l15;
            float val = coef[rb][r] * acc[rb][ct][r];
            if (wv == 0) osh[idx] = val; else osh[idx] += val;
          }
    }
    __syncthreads();
  }

  // ---- final normalize + query-mask + store ----
  {
    const int row = tid >> 3;            // 0..31
    const int cg = (tid & 7) * 16;       // 0..112
    float mstar = msh[0][row];
#pragma unroll
    for (int wv = 1; wv < NWV; ++wv) mstar = fmaxf(mstar, msh[wv][row]);
    float lstar = 0.f;
#pragma unroll
    for (int wv = 0; wv < NWV; ++wv)
      lstar += fast_exp2(msh[wv][row] - mstar) * lsh[wv][row];
    const int qr = qbase + row;
    const float f = ((mask_q[(size_t)b * TQ + qr] != 0) ? 1.f : 0.f) / lstar;
    float* orow = out + ((size_t)b * TQ + qr) * DD + cg;
#pragma unroll
    for (int i4 = 0; i4 < 4; ++i4) {
      float4 p = *(float4*)&osh[row * 132 + cg + i4 * 4];
      float4 o; o.x = p.x * f; o.y = p.y * f; o.z = p.z * f; o.w = p.w * f;
      *(float4*)(orow + i4 * 4) = o;
    }
  }
}

// ---------------- fallback (round-1 kernel) if ws too small --------------------
__global__ __launch_bounds__(64, 4) void attn_f32_kernel(
    const float* __restrict__ q, const float* __restrict__ v,
    const float* __restrict__ k, const float* __restrict__ scale_p,
    const int* __restrict__ mask_q, const int* __restrict__ mask_v,
    float* __restrict__ out)
{
  __shared__ __align__(16) _Float16 plds[16 * 40];
  const int lane = threadIdx.x & 63;
  const int l15 = lane & 15, lg = lane >> 4;
  const int qblocks = TQ / 16;
  const int b = blockIdx.x / qblocks, qb = blockIdx.x % qblocks;
  const int qbase = qb * 16;
  const float scale = scale_p[0];
  const float* qp = q + ((size_t)b * TQ + qbase) * DD;
  const float* kbase = k + (size_t)b * TV * DD;
  const float* vbase = v + (size_t)b * TV * DD;
  const int* mvb = mask_v + b * TV;
  f16x8 qf[4];
#pragma unroll
  for (int kc = 0; kc < 4; ++kc) {
    float4 a = *(const float4*)(qp + (size_t)l15 * DD + kc * 32 + lg * 8);
    float4 bb = *(const float4*)(qp + (size_t)l15 * DD + kc * 32 + lg * 8 + 4);
    f16x8 h; h[0]=(_Float16)a.x;h[1]=(_Float16)a.y;h[2]=(_Float16)a.z;h[3]=(_Float16)a.w;
    h[4]=(_Float16)bb.x;h[5]=(_Float16)bb.y;h[6]=(_Float16)bb.z;h[7]=(_Float16)bb.w;
    qf[kc]=h;
  }
  f32x4 acc[8];
#pragma unroll
  for (int i = 0; i < 8; ++i) acc[i] = (f32x4){0.f,0.f,0.f,0.f};
  float m[4], lsum[4];
#pragma unroll
  for (int r = 0; r < 4; ++r) { m[r] = -3.0e38f; lsum[r] = 0.f; }
  for (int kt = 0; kt < TV; kt += KVT) {
    f32x4 s0 = {0,0,0,0}, s1 = {0,0,0,0};
#pragma unroll
    for (int kc = 0; kc < 4; ++kc) {
      const float* kp0 = kbase + (size_t)(kt + l15) * DD + kc * 32 + lg * 8;
      float4 a = *(const float4*)kp0; float4 bb = *(const float4*)(kp0 + 4);
      f16x8 kf0; kf0[0]=(_Float16)a.x;kf0[1]=(_Float16)a.y;kf0[2]=(_Float16)a.z;kf0[3]=(_Float16)a.w;
      kf0[4]=(_Float16)bb.x;kf0[5]=(_Float16)bb.y;kf0[6]=(_Float16)bb.z;kf0[7]=(_Float16)bb.w;
      s0 = __builtin_amdgcn_mfma_f32_16x16x32_f16(qf[kc], kf0, s0, 0, 0, 0);
      const float* kp1 = kbase + (size_t)(kt + 16 + l15) * DD + kc * 32 + lg * 8;
      a = *(const float4*)kp1; bb = *(const float4*)(kp1 + 4);
      f16x8 kf1; kf1[0]=(_Float16)a.x;kf1[1]=(_Float16)a.y;kf1[2]=(_Float16)a.z;kf1[3]=(_Float16)a.w;
      kf1[4]=(_Float16)bb.x;kf1[5]=(_Float16)bb.y;kf1[6]=(_Float16)bb.z;kf1[7]=(_Float16)bb.w;
      s1 = __builtin_amdgcn_mfma_f32_16x16x32_f16(qf[kc], kf1, s1, 0, 0, 0);
    }
    const float a0 = (mvb[kt + l15] != 0) ? 0.f : -1e9f;
    const float a1 = (mvb[kt + 16 + l15] != 0) ? 0.f : -1e9f;
    float pmx[4];
#pragma unroll
    for (int r = 0; r < 4; ++r) {
      s0[r] = s0[r] * scale + a0; s1[r] = s1[r] * scale + a1;
      pmx[r] = fmaxf(s0[r], s1[r]);
    }
#pragma unroll
    for (int off = 1; off < 16; off <<= 1)
#pragma unroll
      for (int r = 0; r < 4; ++r) pmx[r] = fmaxf(pmx[r], __shfl_xor(pmx[r], off, 64));
    float al[4], ps[4];
#pragma unroll
    for (int r = 0; r < 4; ++r) {
      float mn = fmaxf(m[r], pmx[r]);
      al[r] = __expf(m[r] - mn); m[r] = mn;
      float p0 = __expf(s0[r] - mn), p1 = __expf(s1[r] - mn);
      ps[r] = p0 + p1;
      int row = lg * 4 + r;
      plds[row * 40 + l15] = (_Float16)p0;
      plds[row * 40 + 16 + l15] = (_Float16)p1;
    }
#pragma unroll
    for (int off = 1; off < 16; off <<= 1)
#pragma unroll
      for (int r = 0; r < 4; ++r) ps[r] += __shfl_xor(ps[r], off, 64);
#pragma unroll
    for (int r = 0; r < 4; ++r) {
      lsum[r] = lsum[r] * al[r] + ps[r];
#pragma unroll
      for (int ct = 0; ct < 8; ++ct) acc[ct][r] *= al[r];
    }
    f16x8 pa = *(const f16x8*)&plds[l15 * 40 + lg * 8];
#pragma unroll
    for (int ct = 0; ct < 8; ++ct) {
      const float* vp = vbase + (size_t)(kt + lg * 8) * DD + ct * 16 + l15;
      f16x8 vfx;
#pragma unroll
      for (int j = 0; j < 8; ++j) vfx[j] = (_Float16)vp[(size_t)j * DD];
      acc[ct] = __builtin_amdgcn_mfma_f32_16x16x32_f16(pa, vfx, acc[ct], 0, 0, 0);
    }
  }
  const int* mqb = mask_q + b * TQ;
#pragma unroll
  for (int r = 0; r < 4; ++r) {
    int row = lg * 4 + r;
    int qr = qbase + row;
    float f = ((mqb[qr] != 0) ? 1.f : 0.f) / lsum[r];
    float* orow = out + ((size_t)b * TQ + qr) * DD;
#pragma unroll
    for (int ct = 0; ct < 8; ++ct) orow[ct * 16 + l15] = acc[ct][r] * f;
  }
}

extern "C" void kernel_launch(void* const* d_in, const int* in_sizes, int n_in,
                              void* d_out, int out_size, void* d_ws, size_t ws_size,
                              hipStream_t stream) {
  const float* q      = (const float*)d_in[0];
  const float* v      = (const float*)d_in[1];
  const float* k      = (const float*)d_in[2];
  const float* scale  = (const float*)d_in[3];
  const int*   mask_q = (const int*)d_in[4];
  const int*   mask_v = (const int*)d_in[5];
  float* out = (float*)d_out;

  const size_t need = 2ull * NB * TV * DD * sizeof(_Float16);  // 8 MB (K + V^T)
  if (ws_size >= need) {
    _Float16* kh2 = (_Float16*)d_ws;
    _Float16* vt2 = kh2 + (size_t)NB * TV * DD;
    hipLaunchKernelGGL(prepass_kernel, dim3(512 + 2048), dim3(256), 0, stream,
                       k, v, kh2, vt2);
    hipLaunchKernelGGL(attn_main, dim3(NB * (TQ / 32)), dim3(256), 0, stream,
                       q, scale, kh2, vt2, mask_q, mask_v, out);
  } else {
    hipLaunchKernelGGL(attn_f32_kernel, dim3(NB * (TQ / 16)), dim3(64), 0, stream,
                       q, v, k, scale, mask_q, mask_v, out);
  }
}

// Round 15
// 53.740 us; speedup vs baseline: 1.3899x; 1.0491x over previous
//
#include <hip/hip_runtime.h>
#include <cstddef>

#define NB 8
#define TQ 2048
#define TV 2048
#define DD 128
#define KVT 32
#define NWV 4           // waves per block; chunk = 512 KV rows/wave (PROVEN shape)
#define CHW (TV / NWV)  // 512
#define NT  (CHW / KVT) // 16 tiles per wave
#define LOG2E 1.4426950408889634f

typedef _Float16 f16x8 __attribute__((ext_vector_type(8)));
typedef _Float16 f16x4 __attribute__((ext_vector_type(4)));
typedef float f32x4 __attribute__((ext_vector_type(4)));

__device__ __forceinline__ float fast_exp2(float x) {
  return __builtin_amdgcn_exp2f(x);      // v_exp_f32 (computes 2^x)
}

// ------- prepass -----------------------------------------------------------
// kh2: f16(k) tiled [B][64 kt][4 kc][32 Row][32 dk], rows PERMUTED so that the
//      swapped-QK^T MFMA lands scores at kv = 8*lg + 4*kvf + r (in-register P).
// vt2: f16(v)^T tiled [B][64 kt][128 d][32 kv], masked kv columns ZEROED.
// indb: f16 indicator [B][TV]  (1 = valid kv, 0 = masked)
__global__ __launch_bounds__(256) void prepass_kernel(
    const float* __restrict__ k, const float* __restrict__ v,
    const int* __restrict__ mask_v,
    _Float16* __restrict__ kh2, _Float16* __restrict__ vt2,
    _Float16* __restrict__ indb)
{
  __shared__ _Float16 tlds[32 * 34];
  const int tid = threadIdx.x;
  const int bid = blockIdx.x;
  if (bid < 512) {                        // K tiles: one 32x128 tile per block
    int b = bid >> 6, kt = bid & 63;
    int row = tid >> 3, d0 = (tid & 7) * 4;          // row = original kv 0..31
    int R = 16 * ((row >> 2) & 1) + 4 * (row >> 3) + (row & 3);  // storage row
    const float* src = k + ((size_t)(b * TV + kt * 32 + row)) * DD;
    _Float16* dst = kh2 + ((size_t)(b * 64 + kt)) * 4096;
#pragma unroll
    for (int it = 0; it < 4; ++it) {      // kc = it
      float4 x = *(const float4*)(src + it * 32 + d0);
      f16x4 h; h[0] = (_Float16)x.x; h[1] = (_Float16)x.y;
      h[2] = (_Float16)x.z; h[3] = (_Float16)x.w;
      *(f16x4*)(dst + it * 1024 + R * 32 + d0) = h;
    }
  } else if (bid < 512 + 2048) {          // V transpose tiles 32x32 (masked->0)
    int tb = bid - 512;                   // 8 b * 64 kt * 4 dt
    int b = tb >> 8, rem = tb & 255;
    int kt = rem >> 2, dt = rem & 3;
    int r = tid >> 3, c0 = (tid & 7) * 4;
    float mfac = (mask_v[(size_t)b * TV + kt * 32 + r] != 0) ? 1.f : 0.f;
    float4 x = *(const float4*)&v[((size_t)b * TV + kt * 32 + r) * DD + dt * 32 + c0];
    tlds[(c0 + 0) * 34 + r] = (_Float16)(mfac * x.x);
    tlds[(c0 + 1) * 34 + r] = (_Float16)(mfac * x.y);
    tlds[(c0 + 2) * 34 + r] = (_Float16)(mfac * x.z);
    tlds[(c0 + 3) * 34 + r] = (_Float16)(mfac * x.w);
    __syncthreads();
    int dl = tid >> 3, k0 = (tid & 7) * 4;
    f16x4 h;
#pragma unroll
    for (int i = 0; i < 4; ++i) h[i] = tlds[dl * 34 + k0 + i];
    size_t eidx = (((size_t)b * 64 + kt) * 128 + (dt * 32 + dl)) * 32 + k0;
    *(f16x4*)&vt2[eidx] = h;
  } else {                                // indicator build: 16 blocks
    int bid2 = bid - 512 - 2048;
    size_t base = (size_t)bid2 * 1024 + tid * 4;
#pragma unroll
    for (int i = 0; i < 4; ++i)
      indb[base + i] = (mask_v[base + i] != 0) ? (_Float16)1.f : (_Float16)0.f;
  }
}

// ------- main: grid 512 (b=blk&7), 4 waves x 32 Q rows x 512-KV chunk ----------
// Swapped QK^T + permuted K rows -> P fully in-register, NO LDS in the hot loop.
// Mask bias applied IN-REGISTER from the indicator (keeps m valid-only: the
// r13/r14 failure was masked scores poisoning m -> valid P underflowed f16).
__global__ __launch_bounds__(256, 2) void attn_main(
    const float* __restrict__ q, const float* __restrict__ scale_p,
    const _Float16* __restrict__ kh2, const _Float16* __restrict__ vt2,
    const _Float16* __restrict__ indb,
    const int* __restrict__ mask_q, float* __restrict__ out)
{
  __shared__ __align__(16) float osh[32 * 132];
  __shared__ float msh[NWV][32], lsh[NWV][32];

  const int tid = threadIdx.x;
  const int w = tid >> 6;
  const int lane = tid & 63;
  const int l15 = lane & 15, lg = lane >> 4;

  const int b = blockIdx.x & 7;            // batch -> XCD affinity (proven mapping)
  const int qg = blockIdx.x >> 3;          // 0..63
  const int qbase = qg * 32;

  const _Float16* ktiles = kh2 + (size_t)b * 64 * 4096;
  const _Float16* vtiles = vt2 + (size_t)b * 64 * 4096;
  const _Float16* indbt = indb + (size_t)b * TV;

  // ---- fused Q cast with scale*log2e (B-operand: col = l15 = q row) ----
  const float sc2 = scale_p[0] * LOG2E;
  f16x8 qf[2][4];
#pragma unroll
  for (int rb = 0; rb < 2; ++rb)
#pragma unroll
    for (int kc = 0; kc < 4; ++kc) {
      const float* qp = q + ((size_t)b * TQ + qbase + rb * 16 + l15) * DD + kc * 32 + lg * 8;
      float4 xa = *(const float4*)qp;
      float4 xb = *(const float4*)(qp + 4);
      f16x8 h;
      h[0] = (_Float16)(sc2 * xa.x); h[1] = (_Float16)(sc2 * xa.y);
      h[2] = (_Float16)(sc2 * xa.z); h[3] = (_Float16)(sc2 * xa.w);
      h[4] = (_Float16)(sc2 * xb.x); h[5] = (_Float16)(sc2 * xb.y);
      h[6] = (_Float16)(sc2 * xb.z); h[7] = (_Float16)(sc2 * xb.w);
      qf[rb][kc] = h;
    }

  f32x4 acc[2][8];
  f32x4 accl[2];
#pragma unroll
  for (int rb = 0; rb < 2; ++rb) {
    accl[rb] = (f32x4){0.f, 0.f, 0.f, 0.f};
#pragma unroll
    for (int ct = 0; ct < 8; ++ct) acc[rb][ct] = (f32x4){0.f, 0.f, 0.f, 0.f};
  }
  float m[2];                               // per-lane running max, q = l15
  m[0] = -3.0e38f; m[1] = -3.0e38f;

  const int tbase = w * NT;

#pragma unroll
  for (int t = 0; t < NT; ++t) {
    const int tile = tbase + t;
    const _Float16* ktb = ktiles + (size_t)tile * 4096;
    const _Float16* vtb = vtiles + (size_t)tile * 4096;

    // ---- QK^T swapped: s[kvf][qf] = K_frag x Q_frag ----
    f32x4 s[2][2];
    s[0][0] = (f32x4){0,0,0,0}; s[0][1] = (f32x4){0,0,0,0};
    s[1][0] = (f32x4){0,0,0,0}; s[1][1] = (f32x4){0,0,0,0};
    __builtin_amdgcn_s_setprio(1);
#pragma unroll
    for (int kc = 0; kc < 4; ++kc) {
      f16x8 kf0 = *(const f16x8*)(ktb + kc * 1024 + l15 * 32 + lg * 8);
      f16x8 kf1 = *(const f16x8*)(ktb + kc * 1024 + (16 + l15) * 32 + lg * 8);
      s[0][0] = __builtin_amdgcn_mfma_f32_16x16x32_f16(kf0, qf[0][kc], s[0][0], 0, 0, 0);
      s[0][1] = __builtin_amdgcn_mfma_f32_16x16x32_f16(kf0, qf[1][kc], s[0][1], 0, 0, 0);
      s[1][0] = __builtin_amdgcn_mfma_f32_16x16x32_f16(kf1, qf[0][kc], s[1][0], 0, 0, 0);
      s[1][1] = __builtin_amdgcn_mfma_f32_16x16x32_f16(kf1, qf[1][kc], s[1][1], 0, 0, 0);
    }
    __builtin_amdgcn_s_setprio(0);

    // ---- indicator FIRST (softmax waits only on it), then V (PV waits) ----
    f16x8 indf = *(const f16x8*)(indbt + tile * 32 + lg * 8);
    f16x8 vf[8];
#pragma unroll
    for (int ct = 0; ct < 8; ++ct)
      vf[ct] = *(const f16x8*)(vtb + (ct * 16 + l15) * 32 + lg * 8);

    // ---- mask bias in-register: bias[j] = (ind-1)*60000 (0 valid / -60000) --
    float bias[8];
#pragma unroll
    for (int j = 0; j < 8; ++j) bias[j] = ((float)indf[j] - 1.f) * 60000.f;

    // ---- in-register softmax: lane holds 8 scores of q-row l15 per qf ----
    // score slot (kvf, r) = kv 8*lg + 4*kvf + r; bias index j = 4*kvf + r
    f16x8 pa[2];
#pragma unroll
    for (int rb = 0; rb < 2; ++rb) {
#pragma unroll
      for (int r = 0; r < 4; ++r) {
        s[0][rb][r] += bias[r];
        s[1][rb][r] += bias[4 + r];
      }
      float pm = fmaxf(fmaxf(fmaxf(s[0][rb][0], s[0][rb][1]), fmaxf(s[0][rb][2], s[0][rb][3])),
                       fmaxf(fmaxf(s[1][rb][0], s[1][rb][1]), fmaxf(s[1][rb][2], s[1][rb][3])));
      pm = fmaxf(pm, __shfl_xor(pm, 16, 64));
      pm = fmaxf(pm, __shfl_xor(pm, 32, 64));        // row max over all 32 kv
      if (__any(pm > m[rb] + 11.5f)) {               // rare rescale path
        float mn = fmaxf(m[rb], pm);
        float alpha = fast_exp2(m[rb] - mn);         // per-lane, q = l15
        m[rb] = mn;
        f32x4 alv;
#pragma unroll
        for (int r = 0; r < 4; ++r)
          alv[r] = __shfl(alpha, lg * 4 + r, 64);    // alpha of q-row lg*4+r
        accl[rb] *= alv;
#pragma unroll
        for (int ct = 0; ct < 8; ++ct) acc[rb][ct] *= alv;
      }
      // explicit per-element f16 pack (unambiguous ordering)
      f16x8 p;
      p[0] = (_Float16)fast_exp2(s[0][rb][0] - m[rb]);
      p[1] = (_Float16)fast_exp2(s[0][rb][1] - m[rb]);
      p[2] = (_Float16)fast_exp2(s[0][rb][2] - m[rb]);
      p[3] = (_Float16)fast_exp2(s[0][rb][3] - m[rb]);
      p[4] = (_Float16)fast_exp2(s[1][rb][0] - m[rb]);
      p[5] = (_Float16)fast_exp2(s[1][rb][1] - m[rb]);
      p[6] = (_Float16)fast_exp2(s[1][rb][2] - m[rb]);
      p[7] = (_Float16)fast_exp2(s[1][rb][3] - m[rb]);
      pa[rb] = p;                                    // k-slot j = kv 8*lg+j
    }

    // ---- PV + indicator row-sum (all in-register) ----
    __builtin_amdgcn_s_setprio(1);
#pragma unroll
    for (int ct = 0; ct < 8; ++ct) {
      acc[0][ct] = __builtin_amdgcn_mfma_f32_16x16x32_f16(pa[0], vf[ct], acc[0][ct], 0, 0, 0);
      acc[1][ct] = __builtin_amdgcn_mfma_f32_16x16x32_f16(pa[1], vf[ct], acc[1][ct], 0, 0, 0);
    }
    accl[0] = __builtin_amdgcn_mfma_f32_16x16x32_f16(pa[0], indf, accl[0], 0, 0, 0);
    accl[1] = __builtin_amdgcn_mfma_f32_16x16x32_f16(pa[1], indf, accl[1], 0, 0, 0);
    __builtin_amdgcn_s_setprio(0);
  }

  // ---- publish per-wave stats ----
  if (lg == 0) {                           // lanes 0-15: m for q-row l15
    msh[w][l15]      = m[0];
    msh[w][16 + l15] = m[1];
  }
  if (l15 == 0) {
#pragma unroll
    for (int rb = 0; rb < 2; ++rb)
#pragma unroll
      for (int r = 0; r < 4; ++r)
        lsh[w][rb * 16 + lg * 4 + r] = accl[rb][r];
  }
  __syncthreads();

  // per-wave rescale coefficient to the block max (acc layout: q = lg*4+r)
  float coef[2][4];
#pragma unroll
  for (int rb = 0; rb < 2; ++rb)
#pragma unroll
    for (int r = 0; r < 4; ++r) {
      int row = rb * 16 + lg * 4 + r;
      float mstar = msh[0][row];
#pragma unroll
      for (int wv = 1; wv < NWV; ++wv) mstar = fmaxf(mstar, msh[wv][row]);
      coef[rb][r] = fast_exp2(msh[w][row] - mstar);
    }

  // sequential accumulate into osh (NWV barriers, epilogue-only)
#pragma unroll
  for (int wv = 0; wv < NWV; ++wv) {
    if (w == wv) {
#pragma unroll
      for (int rb = 0; rb < 2; ++rb)
#pragma unroll
        for (int ct = 0; ct < 8; ++ct)
#pragma unroll
          for (int r = 0; r < 4; ++r) {
            int idx = (rb * 16 + lg * 4 + r) * 132 + ct * 16 + l15;
            float val = coef[rb][r] * acc[rb][ct][r];
            if (wv == 0) osh[idx] = val; else osh[idx] += val;
          }
    }
    __syncthreads();
  }

  // ---- final normalize + query-mask + store ----
  {
    const int row = tid >> 3;            // 0..31
    const int cg = (tid & 7) * 16;       // 0..112
    float mstar = msh[0][row];
#pragma unroll
    for (int wv = 1; wv < NWV; ++wv) mstar = fmaxf(mstar, msh[wv][row]);
    float lstar = 0.f;
#pragma unroll
    for (int wv = 0; wv < NWV; ++wv)
      lstar += fast_exp2(msh[wv][row] - mstar) * lsh[wv][row];
    const int qr = qbase + row;
    const float f = ((mask_q[(size_t)b * TQ + qr] != 0) ? 1.f : 0.f) / lstar;
    float* orow = out + ((size_t)b * TQ + qr) * DD + cg;
#pragma unroll
    for (int i4 = 0; i4 < 4; ++i4) {
      float4 p = *(float4*)&osh[row * 132 + cg + i4 * 4];
      float4 o; o.x = p.x * f; o.y = p.y * f; o.z = p.z * f; o.w = p.w * f;
      *(float4*)(orow + i4 * 4) = o;
    }
  }
}

// ---------------- fallback (round-1 kernel) if ws too small --------------------
__global__ __launch_bounds__(64, 4) void attn_f32_kernel(
    const float* __restrict__ q, const float* __restrict__ v,
    const float* __restrict__ k, const float* __restrict__ scale_p,
    const int* __restrict__ mask_q, const int* __restrict__ mask_v,
    float* __restrict__ out)
{
  __shared__ __align__(16) _Float16 plds[16 * 40];
  const int lane = threadIdx.x & 63;
  const int l15 = lane & 15, lg = lane >> 4;
  const int qblocks = TQ / 16;
  const int b = blockIdx.x / qblocks, qb = blockIdx.x % qblocks;
  const int qbase = qb * 16;
  const float scale = scale_p[0];
  const float* qp = q + ((size_t)b * TQ + qbase) * DD;
  const float* kbase = k + (size_t)b * TV * DD;
  const float* vbase = v + (size_t)b * TV * DD;
  const int* mvb = mask_v + b * TV;
  f16x8 qf[4];
#pragma unroll
  for (int kc = 0; kc < 4; ++kc) {
    float4 a = *(const float4*)(qp + (size_t)l15 * DD + kc * 32 + lg * 8);
    float4 bb = *(const float4*)(qp + (size_t)l15 * DD + kc * 32 + lg * 8 + 4);
    f16x8 h; h[0]=(_Float16)a.x;h[1]=(_Float16)a.y;h[2]=(_Float16)a.z;h[3]=(_Float16)a.w;
    h[4]=(_Float16)bb.x;h[5]=(_Float16)bb.y;h[6]=(_Float16)bb.z;h[7]=(_Float16)bb.w;
    qf[kc]=h;
  }
  f32x4 acc[8];
#pragma unroll
  for (int i = 0; i < 8; ++i) acc[i] = (f32x4){0.f,0.f,0.f,0.f};
  float m[4], lsum[4];
#pragma unroll
  for (int r = 0; r < 4; ++r) { m[r] = -3.0e38f; lsum[r] = 0.f; }
  for (int kt = 0; kt < TV; kt += KVT) {
    f32x4 s0 = {0,0,0,0}, s1 = {0,0,0,0};
#pragma unroll
    for (int kc = 0; kc < 4; ++kc) {
      const float* kp0 = kbase + (size_t)(kt + l15) * DD + kc * 32 + lg * 8;
      float4 a = *(const float4*)kp0; float4 bb = *(const float4*)(kp0 + 4);
      f16x8 kf0; kf0[0]=(_Float16)a.x;kf0[1]=(_Float16)a.y;kf0[2]=(_Float16)a.z;kf0[3]=(_Float16)a.w;
      kf0[4]=(_Float16)bb.x;kf0[5]=(_Float16)bb.y;kf0[6]=(_Float16)bb.z;kf0[7]=(_Float16)bb.w;
      s0 = __builtin_amdgcn_mfma_f32_16x16x32_f16(qf[kc], kf0, s0, 0, 0, 0);
      const float* kp1 = kbase + (size_t)(kt + 16 + l15) * DD + kc * 32 + lg * 8;
      a = *(const float4*)kp1; bb = *(const float4*)(kp1 + 4);
      f16x8 kf1; kf1[0]=(_Float16)a.x;kf1[1]=(_Float16)a.y;kf1[2]=(_Float16)a.z;kf1[3]=(_Float16)a.w;
      kf1[4]=(_Float16)bb.x;kf1[5]=(_Float16)bb.y;kf1[6]=(_Float16)bb.z;kf1[7]=(_Float16)bb.w;
      s1 = __builtin_amdgcn_mfma_f32_16x16x32_f16(qf[kc], kf1, s1, 0, 0, 0);
    }
    const float a0 = (mvb[kt + l15] != 0) ? 0.f : -1e9f;
    const float a1 = (mvb[kt + 16 + l15] != 0) ? 0.f : -1e9f;
    float pmx[4];
#pragma unroll
    for (int r = 0; r < 4; ++r) {
      s0[r] = s0[r] * scale + a0; s1[r] = s1[r] * scale + a1;
      pmx[r] = fmaxf(s0[r], s1[r]);
    }
#pragma unroll
    for (int off = 1; off < 16; off <<= 1)
#pragma unroll
      for (int r = 0; r < 4; ++r) pmx[r] = fmaxf(pmx[r], __shfl_xor(pmx[r], off, 64));
    float al[4], ps[4];
#pragma unroll
    for (int r = 0; r < 4; ++r) {
      float mn = fmaxf(m[r], pmx[r]);
      al[r] = __expf(m[r] - mn); m[r] = mn;
      float p0 = __expf(s0[r] - mn), p1 = __expf(s1[r] - mn);
      ps[r] = p0 + p1;
      int row = lg * 4 + r;
      plds[row * 40 + l15] = (_Float16)p0;
      plds[row * 40 + 16 + l15] = (_Float16)p1;
    }
#pragma unroll
    for (int off = 1; off < 16; off <<= 1)
#pragma unroll
      for (int r = 0; r < 4; ++r) ps[r] += __shfl_xor(ps[r], off, 64);
#pragma unroll
    for (int r = 0; r < 4; ++r) {
      lsum[r] = lsum[r] * al[r] + ps[r];
#pragma unroll
      for (int ct = 0; ct < 8; ++ct) acc[ct][r] *= al[r];
    }
    f16x8 pa = *(const f16x8*)&plds[l15 * 40 + lg * 8];
#pragma unroll
    for (int ct = 0; ct < 8; ++ct) {
      const float* vp = vbase + (size_t)(kt + lg * 8) * DD + ct * 16 + l15;
      f16x8 vfx;
#pragma unroll
      for (int j = 0; j < 8; ++j) vfx[j] = (_Float16)vp[(size_t)j * DD];
      acc[ct] = __builtin_amdgcn_mfma_f32_16x16x32_f16(pa, vfx, acc[ct], 0, 0, 0);
    }
  }
  const int* mqb = mask_q + b * TQ;
#pragma unroll
  for (int r = 0; r < 4; ++r) {
    int row = lg * 4 + r;
    int qr = qbase + row;
    float f = ((mqb[qr] != 0) ? 1.f : 0.f) / lsum[r];
    float* orow = out + ((size_t)b * TQ + qr) * DD;
#pragma unroll
    for (int ct = 0; ct < 8; ++ct) orow[ct * 16 + l15] = acc[ct][r] * f;
  }
}

extern "C" void kernel_launch(void* const* d_in, const int* in_sizes, int n_in,
                              void* d_out, int out_size, void* d_ws, size_t ws_size,
                              hipStream_t stream) {
  const float* q      = (const float*)d_in[0];
  const float* v      = (const float*)d_in[1];
  const float* k      = (const float*)d_in[2];
  const float* scale  = (const float*)d_in[3];
  const int*   mask_q = (const int*)d_in[4];
  const int*   mask_v = (const int*)d_in[5];
  float* out = (float*)d_out;

  const size_t kvBytes = 2ull * NB * TV * DD * sizeof(_Float16);  // 8 MB
  const size_t indBytes = (size_t)NB * TV * sizeof(_Float16);     // 32 KB
  if (ws_size >= kvBytes + indBytes) {
    _Float16* kh2 = (_Float16*)d_ws;
    _Float16* vt2 = kh2 + (size_t)NB * TV * DD;
    _Float16* indb = vt2 + (size_t)NB * TV * DD;
    hipLaunchKernelGGL(prepass_kernel, dim3(512 + 2048 + 16), dim3(256), 0, stream,
                       k, v, mask_v, kh2, vt2, indb);
    hipLaunchKernelGGL(attn_main, dim3(NB * (TQ / 32)), dim3(256), 0, stream,
                       q, scale, kh2, vt2, indb, mask_q, out);
  } else {
    hipLaunchKernelGGL(attn_f32_kernel, dim3(NB * (TQ / 16)), dim3(64), 0, stream,
                       q, v, k, scale, mask_q, mask_v, out);
  }
}

// Round 16
// 53.067 us; speedup vs baseline: 1.4075x; 1.0127x over previous
//
#include <hip/hip_runtime.h>
#include <cstddef>

#define NB 8
#define TQ 2048
#define TV 2048
#define DD 128
#define KVT 32
#define NWV 4           // waves per block; chunk = 512 KV rows/wave (PROVEN shape)
#define CHW (TV / NWV)  // 512
#define NT  (CHW / KVT) // 16 tiles per wave
#define LOG2E 1.4426950408889634f

typedef _Float16 f16x8 __attribute__((ext_vector_type(8)));
typedef _Float16 f16x4 __attribute__((ext_vector_type(4)));
typedef float f32x4 __attribute__((ext_vector_type(4)));

__device__ __forceinline__ float fast_exp2(float x) {
  return __builtin_amdgcn_exp2f(x);      // v_exp_f32 (computes 2^x)
}

// ------- prepass (unchanged from r15, which passed) --------------------------
// kh2: f16(k) tiled [B][64 kt][4 kc][32 Row][32 dk], rows PERMUTED so that the
//      swapped-QK^T MFMA lands scores at kv = 8*lg + 4*kvf + r (in-register P).
// vt2: f16(v)^T tiled [B][64 kt][128 d][32 kv], masked kv columns ZEROED.
// indb: f16 indicator [B][TV]  (1 = valid kv, 0 = masked)
__global__ __launch_bounds__(256) void prepass_kernel(
    const float* __restrict__ k, const float* __restrict__ v,
    const int* __restrict__ mask_v,
    _Float16* __restrict__ kh2, _Float16* __restrict__ vt2,
    _Float16* __restrict__ indb)
{
  __shared__ _Float16 tlds[32 * 34];
  const int tid = threadIdx.x;
  const int bid = blockIdx.x;
  if (bid < 512) {                        // K tiles: one 32x128 tile per block
    int b = bid >> 6, kt = bid & 63;
    int row = tid >> 3, d0 = (tid & 7) * 4;          // row = original kv 0..31
    int R = 16 * ((row >> 2) & 1) + 4 * (row >> 3) + (row & 3);  // storage row
    const float* src = k + ((size_t)(b * TV + kt * 32 + row)) * DD;
    _Float16* dst = kh2 + ((size_t)(b * 64 + kt)) * 4096;
#pragma unroll
    for (int it = 0; it < 4; ++it) {      // kc = it
      float4 x = *(const float4*)(src + it * 32 + d0);
      f16x4 h; h[0] = (_Float16)x.x; h[1] = (_Float16)x.y;
      h[2] = (_Float16)x.z; h[3] = (_Float16)x.w;
      *(f16x4*)(dst + it * 1024 + R * 32 + d0) = h;
    }
  } else if (bid < 512 + 2048) {          // V transpose tiles 32x32 (masked->0)
    int tb = bid - 512;                   // 8 b * 64 kt * 4 dt
    int b = tb >> 8, rem = tb & 255;
    int kt = rem >> 2, dt = rem & 3;
    int r = tid >> 3, c0 = (tid & 7) * 4;
    float mfac = (mask_v[(size_t)b * TV + kt * 32 + r] != 0) ? 1.f : 0.f;
    float4 x = *(const float4*)&v[((size_t)b * TV + kt * 32 + r) * DD + dt * 32 + c0];
    tlds[(c0 + 0) * 34 + r] = (_Float16)(mfac * x.x);
    tlds[(c0 + 1) * 34 + r] = (_Float16)(mfac * x.y);
    tlds[(c0 + 2) * 34 + r] = (_Float16)(mfac * x.z);
    tlds[(c0 + 3) * 34 + r] = (_Float16)(mfac * x.w);
    __syncthreads();
    int dl = tid >> 3, k0 = (tid & 7) * 4;
    f16x4 h;
#pragma unroll
    for (int i = 0; i < 4; ++i) h[i] = tlds[dl * 34 + k0 + i];
    size_t eidx = (((size_t)b * 64 + kt) * 128 + (dt * 32 + dl)) * 32 + k0;
    *(f16x4*)&vt2[eidx] = h;
  } else {                                // indicator build: 16 blocks
    int bid2 = bid - 512 - 2048;
    size_t base = (size_t)bid2 * 1024 + tid * 4;
#pragma unroll
    for (int i = 0; i < 4; ++i)
      indb[base + i] = (mask_v[base + i] != 0) ? (_Float16)1.f : (_Float16)0.f;
  }
}

// ------- main: grid 512 (b=blk&7), 4 waves x 32 Q rows x 512-KV chunk ----------
// r15 base (in-register P) + one-tile-ahead K/ind prefetch + shfl-free fast path.
__global__ __launch_bounds__(256, 2) void attn_main(
    const float* __restrict__ q, const float* __restrict__ scale_p,
    const _Float16* __restrict__ kh2, const _Float16* __restrict__ vt2,
    const _Float16* __restrict__ indb,
    const int* __restrict__ mask_q, float* __restrict__ out)
{
  __shared__ __align__(16) float osh[32 * 132];
  __shared__ float msh[NWV][32], lsh[NWV][32];

  const int tid = threadIdx.x;
  const int w = tid >> 6;
  const int lane = tid & 63;
  const int l15 = lane & 15, lg = lane >> 4;

  const int b = blockIdx.x & 7;            // batch -> XCD affinity (proven mapping)
  const int qg = blockIdx.x >> 3;          // 0..63
  const int qbase = qg * 32;

  const _Float16* ktiles = kh2 + (size_t)b * 64 * 4096;
  const _Float16* vtiles = vt2 + (size_t)b * 64 * 4096;
  const _Float16* indbt = indb + (size_t)b * TV;

  // ---- fused Q cast with scale*log2e (B-operand: col = l15 = q row) ----
  const float sc2 = scale_p[0] * LOG2E;
  f16x8 qf[2][4];
#pragma unroll
  for (int rb = 0; rb < 2; ++rb)
#pragma unroll
    for (int kc = 0; kc < 4; ++kc) {
      const float* qp = q + ((size_t)b * TQ + qbase + rb * 16 + l15) * DD + kc * 32 + lg * 8;
      float4 xa = *(const float4*)qp;
      float4 xb = *(const float4*)(qp + 4);
      f16x8 h;
      h[0] = (_Float16)(sc2 * xa.x); h[1] = (_Float16)(sc2 * xa.y);
      h[2] = (_Float16)(sc2 * xa.z); h[3] = (_Float16)(sc2 * xa.w);
      h[4] = (_Float16)(sc2 * xb.x); h[5] = (_Float16)(sc2 * xb.y);
      h[6] = (_Float16)(sc2 * xb.z); h[7] = (_Float16)(sc2 * xb.w);
      qf[rb][kc] = h;
    }

  f32x4 acc[2][8];
  f32x4 accl[2];
#pragma unroll
  for (int rb = 0; rb < 2; ++rb) {
    accl[rb] = (f32x4){0.f, 0.f, 0.f, 0.f};
#pragma unroll
    for (int ct = 0; ct < 8; ++ct) acc[rb][ct] = (f32x4){0.f, 0.f, 0.f, 0.f};
  }
  float m[2];                               // per-lane running max, q = l15
  m[0] = -3.0e38f; m[1] = -3.0e38f;

  const int tbase = w * NT;

  // ---- prefetch buffers (parity; all indices compile-time via full unroll) ----
  f16x8 kbuf[2][8];
  f16x8 indbuf[2];

  // prologue: K(0), ind(0)
  {
    const _Float16* kt0 = ktiles + (size_t)tbase * 4096;
#pragma unroll
    for (int kc = 0; kc < 4; ++kc) {
      kbuf[0][2 * kc]     = *(const f16x8*)(kt0 + kc * 1024 + l15 * 32 + lg * 8);
      kbuf[0][2 * kc + 1] = *(const f16x8*)(kt0 + kc * 1024 + (16 + l15) * 32 + lg * 8);
    }
    indbuf[0] = *(const f16x8*)(indbt + tbase * 32 + lg * 8);
  }

#pragma unroll
  for (int t = 0; t < NT; ++t) {
    const int p = t & 1;
    const int tile = tbase + t;

    // ---- QK^T swapped on resident kbuf[p] (loads issued a full tile ago) ----
    f32x4 s[2][2];
    s[0][0] = (f32x4){0,0,0,0}; s[0][1] = (f32x4){0,0,0,0};
    s[1][0] = (f32x4){0,0,0,0}; s[1][1] = (f32x4){0,0,0,0};
    __builtin_amdgcn_s_setprio(1);
#pragma unroll
    for (int kc = 0; kc < 4; ++kc) {
      s[0][0] = __builtin_amdgcn_mfma_f32_16x16x32_f16(kbuf[p][2*kc],   qf[0][kc], s[0][0], 0, 0, 0);
      s[0][1] = __builtin_amdgcn_mfma_f32_16x16x32_f16(kbuf[p][2*kc],   qf[1][kc], s[0][1], 0, 0, 0);
      s[1][0] = __builtin_amdgcn_mfma_f32_16x16x32_f16(kbuf[p][2*kc+1], qf[0][kc], s[1][0], 0, 0, 0);
      s[1][1] = __builtin_amdgcn_mfma_f32_16x16x32_f16(kbuf[p][2*kc+1], qf[1][kc], s[1][1], 0, 0, 0);
    }
    __builtin_amdgcn_s_setprio(0);

    // ---- issue V(t) now (consumed last in this tile -> latency hides) ----
    const _Float16* vtb = vtiles + (size_t)tile * 4096;
    f16x8 vf[8];
#pragma unroll
    for (int ct = 0; ct < 8; ++ct)
      vf[ct] = *(const f16x8*)(vtb + (ct * 16 + l15) * 32 + lg * 8);

    // ---- issue K(t+1)+ind(t+1) into the other parity buffer ----
    if (t + 1 < NT) {
      const _Float16* ktn = ktiles + (size_t)(tile + 1) * 4096;
#pragma unroll
      for (int kc = 0; kc < 4; ++kc) {
        kbuf[p ^ 1][2 * kc]     = *(const f16x8*)(ktn + kc * 1024 + l15 * 32 + lg * 8);
        kbuf[p ^ 1][2 * kc + 1] = *(const f16x8*)(ktn + kc * 1024 + (16 + l15) * 32 + lg * 8);
      }
      indbuf[p ^ 1] = *(const f16x8*)(indbt + (tile + 1) * 32 + lg * 8);
    }

    const f16x8 indf = indbuf[p];           // resident since last tile

    // ---- in-register softmax; NO cross-lane ops on the fast path ----
    // score slot (kvf, r) = kv 8*lg + 4*kvf + r; bias index j = 4*kvf + r
    f16x8 pa[2];
#pragma unroll
    for (int rb = 0; rb < 2; ++rb) {
#pragma unroll
      for (int r = 0; r < 4; ++r) {
        s[0][rb][r] += ((float)indf[r]     - 1.f) * 60000.f;
        s[1][rb][r] += ((float)indf[4 + r] - 1.f) * 60000.f;
      }
      // local (per-lane) max of this lane's 8 scores
      float lm = fmaxf(fmaxf(fmaxf(s[0][rb][0], s[0][rb][1]), fmaxf(s[0][rb][2], s[0][rb][3])),
                       fmaxf(fmaxf(s[1][rb][0], s[1][rb][1]), fmaxf(s[1][rb][2], s[1][rb][3])));
      if (__any(lm > m[rb] + 11.5f)) {      // rare: full rowmax + rescale
        float pm = lm;
        pm = fmaxf(pm, __shfl_xor(pm, 16, 64));
        pm = fmaxf(pm, __shfl_xor(pm, 32, 64));
        float mn = fmaxf(m[rb], pm);
        float alpha = fast_exp2(m[rb] - mn);         // per-lane, q = l15
        m[rb] = mn;
        f32x4 alv;
#pragma unroll
        for (int r = 0; r < 4; ++r)
          alv[r] = __shfl(alpha, lg * 4 + r, 64);    // alpha of q-row lg*4+r
        accl[rb] *= alv;
#pragma unroll
        for (int ct = 0; ct < 8; ++ct) acc[rb][ct] *= alv;
      }
      f16x8 pp;
      pp[0] = (_Float16)fast_exp2(s[0][rb][0] - m[rb]);
      pp[1] = (_Float16)fast_exp2(s[0][rb][1] - m[rb]);
      pp[2] = (_Float16)fast_exp2(s[0][rb][2] - m[rb]);
      pp[3] = (_Float16)fast_exp2(s[0][rb][3] - m[rb]);
      pp[4] = (_Float16)fast_exp2(s[1][rb][0] - m[rb]);
      pp[5] = (_Float16)fast_exp2(s[1][rb][1] - m[rb]);
      pp[6] = (_Float16)fast_exp2(s[1][rb][2] - m[rb]);
      pp[7] = (_Float16)fast_exp2(s[1][rb][3] - m[rb]);
      pa[rb] = pp;                                   // k-slot j = kv 8*lg+j
    }

    // ---- PV + indicator row-sum (all in-register) ----
    __builtin_amdgcn_s_setprio(1);
#pragma unroll
    for (int ct = 0; ct < 8; ++ct) {
      acc[0][ct] = __builtin_amdgcn_mfma_f32_16x16x32_f16(pa[0], vf[ct], acc[0][ct], 0, 0, 0);
      acc[1][ct] = __builtin_amdgcn_mfma_f32_16x16x32_f16(pa[1], vf[ct], acc[1][ct], 0, 0, 0);
    }
    accl[0] = __builtin_amdgcn_mfma_f32_16x16x32_f16(pa[0], indf, accl[0], 0, 0, 0);
    accl[1] = __builtin_amdgcn_mfma_f32_16x16x32_f16(pa[1], indf, accl[1], 0, 0, 0);
    __builtin_amdgcn_s_setprio(0);
  }

  // ---- publish per-wave stats ----
  if (lg == 0) {                           // lanes 0-15: m for q-row l15
    msh[w][l15]      = m[0];
    msh[w][16 + l15] = m[1];
  }
  if (l15 == 0) {
#pragma unroll
    for (int rb = 0; rb < 2; ++rb)
#pragma unroll
      for (int r = 0; r < 4; ++r)
        lsh[w][rb * 16 + lg * 4 + r] = accl[rb][r];
  }
  __syncthreads();

  // per-wave rescale coefficient to the block max (acc layout: q = lg*4+r)
  float coef[2][4];
#pragma unroll
  for (int rb = 0; rb < 2; ++rb)
#pragma unroll
    for (int r = 0; r < 4; ++r) {
      int row = rb * 16 + lg * 4 + r;
      float mstar = msh[0][row];
#pragma unroll
      for (int wv = 1; wv < NWV; ++wv) mstar = fmaxf(mstar, msh[wv][row]);
      coef[rb][r] = fast_exp2(msh[w][row] - mstar);
    }

  // sequential accumulate into osh (NWV barriers, epilogue-only)
#pragma unroll
  for (int wv = 0; wv < NWV; ++wv) {
    if (w == wv) {
#pragma unroll
      for (int rb = 0; rb < 2; ++rb)
#pragma unroll
        for (int ct = 0; ct < 8; ++ct)
#pragma unroll
          for (int r = 0; r < 4; ++r) {
            int idx = (rb * 16 + lg * 4 + r) * 132 + ct * 16 + l15;
            float val = coef[rb][r] * acc[rb][ct][r];
            if (wv == 0) osh[idx] = val; else osh[idx] += val;
          }
    }
    __syncthreads();
  }

  // ---- final normalize + query-mask + store ----
  {
    const int row = tid >> 3;            // 0..31
    const int cg = (tid & 7) * 16;       // 0..112
    float mstar = msh[0][row];
#pragma unroll
    for (int wv = 1; wv < NWV; ++wv) mstar = fmaxf(mstar, msh[wv][row]);
    float lstar = 0.f;
#pragma unroll
    for (int wv = 0; wv < NWV; ++wv)
      lstar += fast_exp2(msh[wv][row] - mstar) * lsh[wv][row];
    const int qr = qbase + row;
    const float f = ((mask_q[(size_t)b * TQ + qr] != 0) ? 1.f : 0.f) / lstar;
    float* orow = out + ((size_t)b * TQ + qr) * DD + cg;
#pragma unroll
    for (int i4 = 0; i4 < 4; ++i4) {
      float4 p = *(float4*)&osh[row * 132 + cg + i4 * 4];
      float4 o; o.x = p.x * f; o.y = p.y * f; o.z = p.z * f; o.w = p.w * f;
      *(float4*)(orow + i4 * 4) = o;
    }
  }
}

// ---------------- fallback (round-1 kernel) if ws too small --------------------
__global__ __launch_bounds__(64, 4) void attn_f32_kernel(
    const float* __restrict__ q, const float* __restrict__ v,
    const float* __restrict__ k, const float* __restrict__ scale_p,
    const int* __restrict__ mask_q, const int* __restrict__ mask_v,
    float* __restrict__ out)
{
  __shared__ __align__(16) _Float16 plds[16 * 40];
  const int lane = threadIdx.x & 63;
  const int l15 = lane & 15, lg = lane >> 4;
  const int qblocks = TQ / 16;
  const int b = blockIdx.x / qblocks, qb = blockIdx.x % qblocks;
  const int qbase = qb * 16;
  const float scale = scale_p[0];
  const float* qp = q + ((size_t)b * TQ + qbase) * DD;
  const float* kbase = k + (size_t)b * TV * DD;
  const float* vbase = v + (size_t)b * TV * DD;
  const int* mvb = mask_v + b * TV;
  f16x8 qf[4];
#pragma unroll
  for (int kc = 0; kc < 4; ++kc) {
    float4 a = *(const float4*)(qp + (size_t)l15 * DD + kc * 32 + lg * 8);
    float4 bb = *(const float4*)(qp + (size_t)l15 * DD + kc * 32 + lg * 8 + 4);
    f16x8 h; h[0]=(_Float16)a.x;h[1]=(_Float16)a.y;h[2]=(_Float16)a.z;h[3]=(_Float16)a.w;
    h[4]=(_Float16)bb.x;h[5]=(_Float16)bb.y;h[6]=(_Float16)bb.z;h[7]=(_Float16)bb.w;
    qf[kc]=h;
  }
  f32x4 acc[8];
#pragma unroll
  for (int i = 0; i < 8; ++i) acc[i] = (f32x4){0.f,0.f,0.f,0.f};
  float m[4], lsum[4];
#pragma unroll
  for (int r = 0; r < 4; ++r) { m[r] = -3.0e38f; lsum[r] = 0.f; }
  for (int kt = 0; kt < TV; kt += KVT) {
    f32x4 s0 = {0,0,0,0}, s1 = {0,0,0,0};
#pragma unroll
    for (int kc = 0; kc < 4; ++kc) {
      const float* kp0 = kbase + (size_t)(kt + l15) * DD + kc * 32 + lg * 8;
      float4 a = *(const float4*)kp0; float4 bb = *(const float4*)(kp0 + 4);
      f16x8 kf0; kf0[0]=(_Float16)a.x;kf0[1]=(_Float16)a.y;kf0[2]=(_Float16)a.z;kf0[3]=(_Float16)a.w;
      kf0[4]=(_Float16)bb.x;kf0[5]=(_Float16)bb.y;kf0[6]=(_Float16)bb.z;kf0[7]=(_Float16)bb.w;
      s0 = __builtin_amdgcn_mfma_f32_16x16x32_f16(qf[kc], kf0, s0, 0, 0, 0);
      const float* kp1 = kbase + (size_t)(kt + 16 + l15) * DD + kc * 32 + lg * 8;
      a = *(const float4*)kp1; bb = *(const float4*)(kp1 + 4);
      f16x8 kf1; kf1[0]=(_Float16)a.x;kf1[1]=(_Float16)a.y;kf1[2]=(_Float16)a.z;kf1[3]=(_Float16)a.w;
      kf1[4]=(_Float16)bb.x;kf1[5]=(_Float16)bb.y;kf1[6]=(_Float16)bb.z;kf1[7]=(_Float16)bb.w;
      s1 = __builtin_amdgcn_mfma_f32_16x16x32_f16(qf[kc], kf1, s1, 0, 0, 0);
    }
    const float a0 = (mvb[kt + l15] != 0) ? 0.f : -1e9f;
    const float a1 = (mvb[kt + 16 + l15] != 0) ? 0.f : -1e9f;
    float pmx[4];
#pragma unroll
    for (int r = 0; r < 4; ++r) {
      s0[r] = s0[r] * scale + a0; s1[r] = s1[r] * scale + a1;
      pmx[r] = fmaxf(s0[r], s1[r]);
    }
#pragma unroll
    for (int off = 1; off < 16; off <<= 1)
#pragma unroll
      for (int r = 0; r < 4; ++r) pmx[r] = fmaxf(pmx[r], __shfl_xor(pmx[r], off, 64));
    float al[4], ps[4];
#pragma unroll
    for (int r = 0; r < 4; ++r) {
      float mn = fmaxf(m[r], pmx[r]);
      al[r] = __expf(m[r] - mn); m[r] = mn;
      float p0 = __expf(s0[r] - mn), p1 = __expf(s1[r] - mn);
      ps[r] = p0 + p1;
      int row = lg * 4 + r;
      plds[row * 40 + l15] = (_Float16)p0;
      plds[row * 40 + 16 + l15] = (_Float16)p1;
    }
#pragma unroll
    for (int off = 1; off < 16; off <<= 1)
#pragma unroll
      for (int r = 0; r < 4; ++r) ps[r] += __shfl_xor(ps[r], off, 64);
#pragma unroll
    for (int r = 0; r < 4; ++r) {
      lsum[r] = lsum[r] * al[r] + ps[r];
#pragma unroll
      for (int ct = 0; ct < 8; ++ct) acc[ct][r] *= al[r];
    }
    f16x8 pa = *(const f16x8*)&plds[l15 * 40 + lg * 8];
#pragma unroll
    for (int ct = 0; ct < 8; ++ct) {
      const float* vp = vbase + (size_t)(kt + lg * 8) * DD + ct * 16 + l15;
      f16x8 vfx;
#pragma unroll
      for (int j = 0; j < 8; ++j) vfx[j] = (_Float16)vp[(size_t)j * DD];
      acc[ct] = __builtin_amdgcn_mfma_f32_16x16x32_f16(pa, vfx, acc[ct], 0, 0, 0);
    }
  }
  const int* mqb = mask_q + b * TQ;
#pragma unroll
  for (int r = 0; r < 4; ++r) {
    int row = lg * 4 + r;
    int qr = qbase + row;
    float f = ((mqb[qr] != 0) ? 1.f : 0.f) / lsum[r];
    float* orow = out + ((size_t)b * TQ + qr) * DD;
#pragma unroll
    for (int ct = 0; ct < 8; ++ct) orow[ct * 16 + l15] = acc[ct][r] * f;
  }
}

extern "C" void kernel_launch(void* const* d_in, const int* in_sizes, int n_in,
                              void* d_out, int out_size, void* d_ws, size_t ws_size,
                              hipStream_t stream) {
  const float* q      = (const float*)d_in[0];
  const float* v      = (const float*)d_in[1];
  const float* k      = (const float*)d_in[2];
  const float* scale  = (const float*)d_in[3];
  const int*   mask_q = (const int*)d_in[4];
  const int*   mask_v = (const int*)d_in[5];
  float* out = (float*)d_out;

  const size_t kvBytes = 2ull * NB * TV * DD * sizeof(_Float16);  // 8 MB
  const size_t indBytes = (size_t)NB * TV * sizeof(_Float16);     // 32 KB
  if (ws_size >= kvBytes + indBytes) {
    _Float16* kh2 = (_Float16*)d_ws;
    _Float16* vt2 = kh2 + (size_t)NB * TV * DD;
    _Float16* indb = vt2 + (size_t)NB * TV * DD;
    hipLaunchKernelGGL(prepass_kernel, dim3(512 + 2048 + 16), dim3(256), 0, stream,
                       k, v, mask_v, kh2, vt2, indb);
    hipLaunchKernelGGL(attn_main, dim3(NB * (TQ / 32)), dim3(256), 0, stream,
                       q, scale, kh2, vt2, indb, mask_q, out);
  } else {
    hipLaunchKernelGGL(attn_f32_kernel, dim3(NB * (TQ / 16)), dim3(64), 0, stream,
                       q, v, k, scale, mask_q, mask_v, out);
  }
}